// Round 2
// baseline (1724.385 us; speedup 1.0000x reference)
//
#include <hip/hip_runtime.h>
#include <hip/hip_bf16.h>

#define KTOT 164
#define KHALF 82
#define KPAD 84   // 84*4B = 336B row stride, 16B-aligned for ds_read_b128

// 10^(-j/4), j=0..3
__constant__ float c_invfreq[4] = {1.0f, 0.56234132519034908f,
                                   0.31622776601683794f, 0.17782794100389228f};

// ---------------------------------------------------------------- prep
__global__ __launch_bounds__(128) void k_prep(
    const float* __restrict__ queries, const float* __restrict__ qpos,
    const int* __restrict__ offsets, int n_off,
    float* __restrict__ x, float* __restrict__ qcs, int* __restrict__ bids) {
  int n = blockIdx.x, d = threadIdx.x;
  x[(size_t)n * 128 + d] = queries[(size_t)n * 128 + d];
  if (d == 0) {
    int bid = 0;
    for (int j = 1; j < n_off; ++j)
      if (offsets[j] <= n) bid = j;   // searchsorted(side='right') - 1
    bids[n] = bid;
  }
  if (d < 8) {
    float p = (d < 4) ? qpos[n * 2 + 0] : qpos[n * 2 + 1];
    float ang = p * c_invfreq[d & 3];
    qcs[n * 16 + d] = cosf(ang);
    qcs[n * 16 + 8 + d] = sinf(ang);
  }
}

// ---------------------------------------------------------------- gather
__global__ __launch_bounds__(128) void k_gather(
    const float* __restrict__ fm, const float* __restrict__ qpos,
    const int* __restrict__ lss, const int* __restrict__ bids,
    __hip_bfloat16* __restrict__ feats, float* __restrict__ kcs,
    unsigned char* __restrict__ valid) {
  int n = blockIdx.x, kk = blockIdx.y, d = threadIdx.x;
  int l, base, diam;
  if (kk < 9)       { l = 0; base = 0;  diam = 3; }
  else if (kk < 34) { l = 1; base = 9;  diam = 5; }
  else if (kk < 83) { l = 2; base = 34; diam = 7; }
  else              { l = 3; base = 83; diam = 9; }
  int local = kk - base;
  int a = local / diam, b = local % diam;
  int Hl = lss[l * 2], Wl = lss[l * 2 + 1];
  float ms0 = (float)lss[0], ms1 = (float)lss[1];
  float si = (float)Hl / ms0, sj = (float)Wl / ms1;
  float p0 = qpos[n * 2], p1 = qpos[n * 2 + 1];
  int ci = (int)floorf(p0 * si), cj = (int)floorf(p1 * sj);
  int gi = ci + a - diam / 2, gj = cj + b - diam / 2;
  bool v = (gi >= 0) & (gi < Hl) & (gj >= 0) & (gj < Wl);
  int cci = min(max(gi, 0), Hl - 1), ccj = min(max(gj, 0), Wl - 1);
  const float* row = fm + ((((size_t)bids[n] * 256 + cci) * 256 + ccj) * 4 + l) * 128;
  float f = v ? row[d] : 0.0f;
  feats[((size_t)n * KTOT + kk) * 128 + d] = __float2bfloat16(f);
  if (d < 8) {
    float kp = (d < 4) ? (((float)gi + 0.5f) / si) : (((float)gj + 0.5f) / sj);
    float ang = kp * c_invfreq[d & 3];
    kcs[((size_t)n * KTOT + kk) * 16 + d] = cosf(ang);
    kcs[((size_t)n * KTOT + kk) * 16 + 8 + d] = sinf(ang);
  }
  if (d == 0) valid[(size_t)n * KTOT + kk] = v ? 1 : 0;
}

// ---------------------------------------------------------------- layernorm helper
__device__ __forceinline__ void block_meanvar_128(float v, float& m, float& rinv,
                                                  float* red, int d) {
  float s = v, s2 = v * v;
  #pragma unroll
  for (int o = 32; o; o >>= 1) { s += __shfl_down(s, o); s2 += __shfl_down(s2, o); }
  int wave = d >> 6, lane = d & 63;
  if (lane == 0) { red[wave * 2] = s; red[wave * 2 + 1] = s2; }
  __syncthreads();
  float S = red[0] + red[2], S2 = red[1] + red[3];
  m = S * (1.0f / 128.0f);
  float var = S2 * (1.0f / 128.0f) - m * m;
  rinv = rsqrtf(var + 1e-5f);
}

__global__ __launch_bounds__(128) void k_ln(
    const float* __restrict__ x, const float* __restrict__ g,
    const float* __restrict__ b, float* __restrict__ h) {
  int n = blockIdx.x, d = threadIdx.x;
  __shared__ float red[4];
  float v = x[(size_t)n * 128 + d];
  float m, r;
  block_meanvar_128(v, m, r, red, d);
  h[(size_t)n * 128 + d] = (v - m) * r * g[d] + b[d];
}

// ---------------------------------------------------------------- q projection + rope
__global__ __launch_bounds__(128) void k_qproj(
    const float* __restrict__ h, const float* __restrict__ Wq,
    const float* __restrict__ qcs, float* __restrict__ q) {
  int n = blockIdx.x, d = threadIdx.x;
  __shared__ float hs[128], raw[128];
  hs[d] = h[(size_t)n * 128 + d];
  __syncthreads();
  float acc = 0.f;
  for (int c = 0; c < 128; ++c) acc += hs[c] * Wq[c * 128 + d];
  raw[d] = acc;
  __syncthreads();
  int j = (d & 15) >> 1;
  float cc = qcs[n * 16 + j], ss = qcs[n * 16 + 8 + j];
  float out = (d & 1) ? (raw[d - 1] * ss + raw[d] * cc)
                      : (raw[d] * cc - raw[d + 1] * ss);
  q[(size_t)n * 128 + d] = out;
}

// ---------------------------------------------------------------- fused attention
// KB keys at a time: weight row loaded once, applied to KB keys (8x less L2 traffic)
template <int KB>
__device__ __forceinline__ void attn_batch(
    const float* ffT, int kk0, int kbase,
    const float* __restrict__ Wk, const float* __restrict__ Wv,
    const float* __restrict__ kcsrow, const unsigned char* __restrict__ vrow,
    float qd, int j, bool odd, int d, float& m, float& l, float& o) {
  float ak[KB], av[KB];
  #pragma unroll
  for (int u = 0; u < KB; ++u) { ak[u] = 0.f; av[u] = 0.f; }
  const float* fr = ffT + kk0;
  for (int c = 0; c < 128; ++c) {
    float wk = Wk[c * 128 + d];
    float wv = Wv[c * 128 + d];
    #pragma unroll
    for (int u = 0; u < KB; ++u) {
      float f = fr[c * KPAD + u];
      ak[u] += f * wk;
      av[u] += f * wv;
    }
  }
  #pragma unroll
  for (int u = 0; u < KB; ++u) {
    int kk = kbase + kk0 + u;
    float akp = __shfl_xor(ak[u], 1);
    float kc = kcsrow[kk * 16 + j], ks = kcsrow[kk * 16 + 8 + j];
    float kro = odd ? (akp * ks + ak[u] * kc) : (ak[u] * kc - akp * ks);
    float prod = qd * kro;
    #pragma unroll
    for (int off = 8; off; off >>= 1) prod += __shfl_xor(prod, off, 16);
    float s = vrow[kk] ? prod * 0.25f : -1e9f;   // / sqrt(16), valid mask
    float mnew = fmaxf(m, s);
    float sc = expf(m - mnew);
    float pp = expf(s - mnew);
    l = l * sc + pp;
    o = o * sc + pp * av[u];
    m = mnew;
  }
}

__global__ __launch_bounds__(128) void k_attn(
    const float* __restrict__ q, const __hip_bfloat16* __restrict__ feats,
    const float* __restrict__ kcs, const unsigned char* __restrict__ valid,
    const float* __restrict__ Wk, const float* __restrict__ Wv,
    const float* __restrict__ Wo, float* __restrict__ x) {
  int n = blockIdx.x, d = threadIdx.x;
  __shared__ float ffT[128 * KPAD];   // transposed feats, one half (82 keys), 43KB
  __shared__ float ol[128];
  float qd = q[(size_t)n * 128 + d];
  float m = -INFINITY, l = 0.0f, o = 0.0f;
  const __hip_bfloat16* fbase = feats + (size_t)n * KTOT * 128;
  const float* kcsrow = kcs + (size_t)n * KTOT * 16;
  const unsigned char* vrow = valid + (size_t)n * KTOT;
  int j = (d & 15) >> 1;
  bool odd = d & 1;
  for (int half = 0; half < 2; ++half) {
    int kbase = half * KHALF;
    __syncthreads();   // previous half's reads done
    for (int t = 0; t < KHALF; ++t)   // coalesced read, transposed LDS write
      ffT[d * KPAD + t] = __bfloat162float(fbase[(size_t)(kbase + t) * 128 + d]);
    __syncthreads();
    int kk0 = 0;
    for (; kk0 + 8 <= KHALF; kk0 += 8)
      attn_batch<8>(ffT, kk0, kbase, Wk, Wv, kcsrow, vrow, qd, j, odd, d, m, l, o);
    attn_batch<2>(ffT, kk0, kbase, Wk, Wv, kcsrow, vrow, qd, j, odd, d, m, l, o);
  }
  o /= l;
  __syncthreads();
  ol[d] = o;
  __syncthreads();
  float acc = 0.f;
  for (int c = 0; c < 128; ++c) acc += ol[c] * Wo[c * 128 + d];
  x[(size_t)n * 128 + d] += acc;
}

// ---------------------------------------------------------------- fused FFN block
__global__ __launch_bounds__(128) void k_ffn(
    float* __restrict__ x, const float* __restrict__ g, const float* __restrict__ b,
    const float* __restrict__ W1, const float* __restrict__ b1,
    const float* __restrict__ W2, const float* __restrict__ b2) {
  int n = blockIdx.x, d = threadIdx.x;
  __shared__ float red[4];
  __shared__ float h2[128];
  __shared__ float t[512];
  float v = x[(size_t)n * 128 + d];
  float m, r;
  block_meanvar_128(v, m, r, red, d);
  h2[d] = (v - m) * r * g[d] + b[d];
  __syncthreads();
  #pragma unroll
  for (int rr = 0; rr < 4; ++rr) {
    int jj = d + 128 * rr;
    float acc = b1[jj];
    for (int c = 0; c < 128; ++c) acc += h2[c] * W1[c * 512 + jj];
    float inner = 0.7978845608028654f * (acc + 0.044715f * acc * acc * acc);
    t[jj] = 0.5f * acc * (1.0f + tanhf(inner));  // jax.nn.gelu approximate=True
  }
  __syncthreads();
  float acc = b2[d];
  for (int jj = 0; jj < 512; ++jj) acc += t[jj] * W2[jj * 128 + d];
  x[(size_t)n * 128 + d] = v + acc;
}

// ---------------------------------------------------------------- final logits
__global__ __launch_bounds__(256) void k_logits(
    const float* __restrict__ x, const float* __restrict__ qpos,
    const int* __restrict__ lss, const int* __restrict__ bids,
    const float* __restrict__ fm, float* __restrict__ out) {
  int n = blockIdx.x, t = threadIdx.x;
  __shared__ float xs[128];
  if (t < 128) xs[t] = x[(size_t)n * 128 + t];
  __syncthreads();
  int wave = t >> 6, lane = t & 63;
  int Hl = lss[0], Wl = lss[1];
  float p0 = qpos[n * 2], p1 = qpos[n * 2 + 1];
  int ci = (int)floorf(p0), cj = (int)floorf(p1);   // level-0 scale == 1
  size_t bb = (size_t)bids[n] * 256;
  for (int p = wave; p < 49; p += 4) {
    int gi = ci + p / 7 - 3, gj = cj + p % 7 - 3;
    bool v = (gi >= 0) & (gi < Hl) & (gj >= 0) & (gj < Wl);
    int cci = min(max(gi, 0), Hl - 1), ccj = min(max(gj, 0), Wl - 1);
    const float* row = fm + (((bb + cci) * 256 + ccj) * 4 + 0) * 128;
    float s = xs[lane] * row[lane] + xs[lane + 64] * row[lane + 64];
    #pragma unroll
    for (int o = 32; o; o >>= 1) s += __shfl_xor(s, o);
    if (lane == 0) out[(size_t)n * 49 + p] = v ? s : 0.0f;
  }
}

// ---------------------------------------------------------------- launch
extern "C" void kernel_launch(void* const* d_in, const int* in_sizes, int n_in,
                              void* d_out, int out_size, void* d_ws, size_t ws_size,
                              hipStream_t stream) {
  const float* queries = (const float*)d_in[0];
  const int*   offs    = (const int*)d_in[1];
  const float* qpos    = (const float*)d_in[2];
  const float* fm      = (const float*)d_in[3];
  const int*   lss     = (const int*)d_in[4];
  const float* Wq   = (const float*)d_in[5];
  const float* Wk   = (const float*)d_in[6];
  const float* Wv   = (const float*)d_in[7];
  const float* Wo   = (const float*)d_in[8];
  const float* ln1g = (const float*)d_in[9];
  const float* ln1b = (const float*)d_in[10];
  const float* ln2g = (const float*)d_in[11];
  const float* ln2b = (const float*)d_in[12];
  const float* W1   = (const float*)d_in[13];
  const float* b1   = (const float*)d_in[14];
  const float* W2   = (const float*)d_in[15];
  const float* b2   = (const float*)d_in[16];
  const int N = in_sizes[0] / 128;
  const int n_off = in_sizes[1];

  char* p = (char*)d_ws;
  size_t off = 0;
  auto carve = [&](size_t bytes) {
    void* r = p + off;
    off = (off + bytes + 255) & ~(size_t)255;
    return r;
  };
  float* x    = (float*)carve((size_t)N * 128 * 4);
  float* h    = (float*)carve((size_t)N * 128 * 4);
  float* qb   = (float*)carve((size_t)N * 128 * 4);
  float* qcs  = (float*)carve((size_t)N * 16 * 4);
  int*   bids = (int*)carve((size_t)N * 4);
  unsigned char* valid = (unsigned char*)carve((size_t)N * KTOT);
  float* kcs  = (float*)carve((size_t)N * KTOT * 16 * 4);
  __hip_bfloat16* feats = (__hip_bfloat16*)carve((size_t)N * KTOT * 128 * 2);
  (void)n_in; (void)out_size; (void)ws_size;

  k_prep<<<dim3(N), dim3(128), 0, stream>>>(queries, qpos, offs, n_off, x, qcs, bids);
  k_gather<<<dim3(N, KTOT), dim3(128), 0, stream>>>(fm, qpos, lss, bids, feats, kcs, valid);
  for (int li = 0; li < 2; ++li) {
    k_ln<<<dim3(N), dim3(128), 0, stream>>>(x, ln1g + li * 128, ln1b + li * 128, h);
    k_qproj<<<dim3(N), dim3(128), 0, stream>>>(h, Wq + (size_t)li * 128 * 128, qcs, qb);
    k_attn<<<dim3(N), dim3(128), 0, stream>>>(qb, feats, kcs, valid,
                                              Wk + (size_t)li * 128 * 128,
                                              Wv + (size_t)li * 128 * 128,
                                              Wo + (size_t)li * 128 * 128, x);
    k_ffn<<<dim3(N), dim3(128), 0, stream>>>(x, ln2g + li * 128, ln2b + li * 128,
                                             W1 + (size_t)li * 128 * 512, b1 + (size_t)li * 512,
                                             W2 + (size_t)li * 512 * 128, b2 + (size_t)li * 128);
  }
  k_logits<<<dim3(N), dim3(256), 0, stream>>>(x, qpos, lss, bids, fm, (float*)d_out);
}

// Round 4
// 756.429 us; speedup vs baseline: 2.2796x; 2.2796x over previous
//
#include <hip/hip_runtime.h>
#include <hip/hip_bf16.h>

#define KTOT 164
#define AST 136   // A-tile LDS row stride in bf16 elems (136*2=272B, breaks bank conflicts)

typedef __attribute__((ext_vector_type(8))) short short8;
typedef __attribute__((ext_vector_type(4))) float f32x4;

__constant__ float c_invfreq[4] = {1.0f, 0.56234132519034908f,
                                   0.31622776601683794f, 0.17782794100389228f};

__device__ __forceinline__ float bflo(unsigned int u) { return __uint_as_float(u << 16); }
__device__ __forceinline__ float bfhi(unsigned int u) { return __uint_as_float(u & 0xffff0000u); }
__device__ __forceinline__ unsigned short f2bfu(float f) {
  return __bfloat16_as_ushort(__float2bfloat16(f));
}

// ---------------------------------------------------------------- prep
__global__ __launch_bounds__(128) void k_prep(
    const float* __restrict__ queries, const float* __restrict__ qpos,
    const int* __restrict__ offsets, int n_off,
    float* __restrict__ x, float* __restrict__ qcs, int* __restrict__ bids) {
  int n = blockIdx.x, d = threadIdx.x;
  x[(size_t)n * 128 + d] = queries[(size_t)n * 128 + d];
  if (d == 0) {
    int bid = 0;
    for (int j = 1; j < n_off; ++j)
      if (offsets[j] <= n) bid = j;
    bids[n] = bid;
  }
  if (d < 8) {
    float p = (d < 4) ? qpos[n * 2 + 0] : qpos[n * 2 + 1];
    float ang = p * c_invfreq[d & 3];
    qcs[n * 16 + d] = cosf(ang);
    qcs[n * 16 + 8 + d] = sinf(ang);
  }
}

// ---------------------------------------------------------------- gather (block per query)
__global__ __launch_bounds__(256) void k_gather(
    const float* __restrict__ fm, const float* __restrict__ qpos,
    const int* __restrict__ lss, const int* __restrict__ bids,
    __hip_bfloat16* __restrict__ feats, float* __restrict__ kcs,
    unsigned char* __restrict__ valid) {
  int n = blockIdx.x, tid = threadIdx.x;
  int sub = tid >> 5;        // key slot in pass (8 keys/pass)
  int c = tid & 31;          // float4 chunk within row
  float p0 = qpos[n * 2], p1 = qpos[n * 2 + 1];
  int bid = bids[n];
  float ms0 = (float)lss[0], ms1 = (float)lss[1];
  for (int base = 0; base < KTOT; base += 8) {
    int kk = base + sub;
    if (kk < KTOT) {
      int l, bse, diam;
      if (kk < 9)       { l = 0; bse = 0;  diam = 3; }
      else if (kk < 34) { l = 1; bse = 9;  diam = 5; }
      else if (kk < 83) { l = 2; bse = 34; diam = 7; }
      else              { l = 3; bse = 83; diam = 9; }
      int local = kk - bse;
      int a = local / diam, b = local % diam;
      int Hl = lss[2 * l], Wl = lss[2 * l + 1];
      float si = (float)Hl / ms0, sj = (float)Wl / ms1;
      int ci = (int)floorf(p0 * si), cj = (int)floorf(p1 * sj);
      int gi = ci + a - diam / 2, gj = cj + b - diam / 2;
      bool v = (gi >= 0) & (gi < Hl) & (gj >= 0) & (gj < Wl);
      int cci = min(max(gi, 0), Hl - 1), ccj = min(max(gj, 0), Wl - 1);
      const float* row = fm + ((((size_t)bid * 256 + cci) * 256 + ccj) * 4 + l) * 128;
      float4 ld = {0.f, 0.f, 0.f, 0.f};
      if (v) ld = *reinterpret_cast<const float4*>(row + c * 4);
      ushort4 st;
      st.x = f2bfu(ld.x); st.y = f2bfu(ld.y); st.z = f2bfu(ld.z); st.w = f2bfu(ld.w);
      *reinterpret_cast<ushort4*>(
          reinterpret_cast<unsigned short*>(feats) + ((size_t)n * KTOT + kk) * 128 + c * 4) = st;
      if (c < 8) {
        float kp = (c < 4) ? (((float)gi + 0.5f) / si) : (((float)gj + 0.5f) / sj);
        float ang = kp * c_invfreq[c & 3];
        kcs[((size_t)n * KTOT + kk) * 16 + c] = cosf(ang);
        kcs[((size_t)n * KTOT + kk) * 16 + 8 + c] = sinf(ang);
      }
      if (c == 31) valid[(size_t)n * KTOT + kk] = v ? 1 : 0;
    }
  }
}

// ---------------------------------------------------------------- layernorm
__device__ __forceinline__ void block_meanvar_128(float v, float& m, float& rinv,
                                                  float* red, int d) {
  float s = v, s2 = v * v;
  #pragma unroll
  for (int o = 32; o; o >>= 1) { s += __shfl_down(s, o); s2 += __shfl_down(s2, o); }
  int wave = d >> 6, lane = d & 63;
  if (lane == 0) { red[wave * 2] = s; red[wave * 2 + 1] = s2; }
  __syncthreads();
  float S = red[0] + red[2], S2 = red[1] + red[3];
  m = S * (1.0f / 128.0f);
  float var = S2 * (1.0f / 128.0f) - m * m;
  rinv = rsqrtf(var + 1e-5f);
}

__global__ __launch_bounds__(128) void k_ln(
    const float* __restrict__ x, const float* __restrict__ g,
    const float* __restrict__ b, float* __restrict__ h) {
  int n = blockIdx.x, d = threadIdx.x;
  __shared__ float red[4];
  float v = x[(size_t)n * 128 + d];
  float m, r;
  block_meanvar_128(v, m, r, red, d);
  h[(size_t)n * 128 + d] = (v - m) * r * g[d] + b[d];
}

// ---------------------------------------------------------------- q projection + rope
__global__ __launch_bounds__(128) void k_qproj(
    const float* __restrict__ h, const float* __restrict__ Wq,
    const float* __restrict__ qcs, float* __restrict__ q) {
  int n = blockIdx.x, d = threadIdx.x;
  __shared__ float hs[128], raw[128];
  hs[d] = h[(size_t)n * 128 + d];
  __syncthreads();
  float acc = 0.f;
  for (int c = 0; c < 128; ++c) acc += hs[c] * Wq[c * 128 + d];
  raw[d] = acc;
  __syncthreads();
  int j = (d & 15) >> 1;
  float cc = qcs[n * 16 + j], ss = qcs[n * 16 + 8 + j];
  float out = (d & 1) ? (raw[d - 1] * ss + raw[d] * cc)
                      : (raw[d] * cc - raw[d + 1] * ss);
  q[(size_t)n * 128 + d] = out;
}

// ---------------------------------------------------------------- K/V projection GEMM (MFMA)
// C[row][d] = feats[row][:] @ W[:][d], rows = flattened (n,kk). blockIdx.y: 0=K, 1=V.
// 4 waves: wave (wm,wn) computes rows [wm*32,+32) x cols [wn*64,+64).
// B-frags (weights) live in registers, loaded once per block. A staged in LDS.
__global__ __launch_bounds__(256) void k_kvproj(
    const __hip_bfloat16* __restrict__ feats, const float* __restrict__ Wk,
    const float* __restrict__ Wv, __hip_bfloat16* __restrict__ kbuf,
    __hip_bfloat16* __restrict__ vbuf, int nrows) {
  __shared__ short Alds[64 * AST];
  const float* __restrict__ W = blockIdx.y ? Wv : Wk;
  unsigned short* __restrict__ out =
      reinterpret_cast<unsigned short*>(blockIdx.y ? vbuf : kbuf);
  const unsigned short* fu = reinterpret_cast<const unsigned short*>(feats);
  int tid = threadIdx.x;
  int w = tid >> 6, lane = tid & 63;
  int wm = w >> 1, wn = w & 1;
  int lr = lane & 15;            // row/col within 16-tile
  int lk = (lane >> 4) * 8;      // k offset within 32
  // load B fragments: bf[nt][ks], element j = W[ks*32+lk+j][wn*64+nt*16+lr]
  short8 bf[4][4];
  #pragma unroll
  for (int nt = 0; nt < 4; ++nt) {
    int col = wn * 64 + nt * 16 + lr;
    #pragma unroll
    for (int ks = 0; ks < 4; ++ks) {
      short8 f;
      #pragma unroll
      for (int j = 0; j < 8; ++j)
        f[j] = (short)f2bfu(W[(ks * 32 + lk + j) * 128 + col]);
      bf[nt][ks] = f;
    }
  }
  int ntiles = (nrows + 63) >> 6;
  for (int t = blockIdx.x; t < ntiles; t += gridDim.x) {
    size_t row0 = (size_t)t * 64;
    __syncthreads();
    #pragma unroll
    for (int p = 0; p < 4; ++p) {
      int chunk = p * 256 + tid;          // 1024 x 16B chunks
      int r = chunk >> 4, c16 = chunk & 15;
      size_t gr = row0 + r;
      if (gr >= (size_t)nrows) gr = nrows - 1;
      short8 v = *reinterpret_cast<const short8*>(fu + gr * 128 + c16 * 8);
      *reinterpret_cast<short8*>(&Alds[r * AST + c16 * 8]) = v;
    }
    __syncthreads();
    f32x4 acc[2][4];
    #pragma unroll
    for (int mt = 0; mt < 2; ++mt)
      #pragma unroll
      for (int nt = 0; nt < 4; ++nt)
        acc[mt][nt] = (f32x4){0.f, 0.f, 0.f, 0.f};
    #pragma unroll
    for (int ks = 0; ks < 4; ++ks) {
      short8 af[2];
      #pragma unroll
      for (int mt = 0; mt < 2; ++mt)
        af[mt] = *reinterpret_cast<const short8*>(
            &Alds[(wm * 32 + mt * 16 + lr) * AST + ks * 32 + lk]);
      #pragma unroll
      for (int mt = 0; mt < 2; ++mt)
        #pragma unroll
        for (int nt = 0; nt < 4; ++nt)
          acc[mt][nt] = __builtin_amdgcn_mfma_f32_16x16x32_bf16(
              af[mt], bf[nt][ks], acc[mt][nt], 0, 0, 0);
    }
    #pragma unroll
    for (int mt = 0; mt < 2; ++mt) {
      #pragma unroll
      for (int nt = 0; nt < 4; ++nt) {
        int col = wn * 64 + nt * 16 + lr;
        #pragma unroll
        for (int r = 0; r < 4; ++r) {
          size_t row = row0 + wm * 32 + mt * 16 + (lane >> 4) * 4 + r;
          if (row < (size_t)nrows)
            out[row * 128 + col] = f2bfu(acc[mt][nt][r]);
        }
      }
    }
  }
}

// ---------------------------------------------------------------- attention (streaming)
// block per query, 4 waves split keys; lane t owns dims (2t, 2t+1).
__global__ __launch_bounds__(256) void k_attn2(
    const float* __restrict__ q, const __hip_bfloat16* __restrict__ kbuf,
    const __hip_bfloat16* __restrict__ vbuf, const float* __restrict__ kcs,
    const unsigned char* __restrict__ valid, const float* __restrict__ Wo,
    float* __restrict__ x) {
  int n = blockIdx.x, tid = threadIdx.x;
  int w = tid >> 6, t = tid & 63;
  __shared__ float sm[4][8], sl[4][8], so[4][128], ol[128], red[2][128];
  float2 qp = *reinterpret_cast<const float2*>(q + (size_t)n * 128 + 2 * t);
  const unsigned int* krow =
      reinterpret_cast<const unsigned int*>(kbuf + (size_t)n * KTOT * 128);
  const unsigned int* vrw =
      reinterpret_cast<const unsigned int*>(vbuf + (size_t)n * KTOT * 128);
  const float* kc = kcs + (size_t)n * KTOT * 16;
  const unsigned char* vd = valid + (size_t)n * KTOT;
  int j = t & 7;
  float m = -INFINITY, l = 0.f, o0 = 0.f, o1 = 0.f;
  for (int kk = w; kk < KTOT; kk += 4) {
    unsigned int ku = krow[kk * 64 + t];
    unsigned int vu = vrw[kk * 64 + t];
    float k0 = bflo(ku), k1 = bfhi(ku);
    float cc = kc[kk * 16 + j], ss = kc[kk * 16 + 8 + j];
    float kr0 = k0 * cc - k1 * ss, kr1 = k0 * ss + k1 * cc;
    float prod = qp.x * kr0 + qp.y * kr1;
    prod += __shfl_xor(prod, 1, 8);
    prod += __shfl_xor(prod, 2, 8);
    prod += __shfl_xor(prod, 4, 8);
    float s = vd[kk] ? prod * 0.25f : -1e9f;
    float mn = fmaxf(m, s);
    float esc = expf(m - mn), pp = expf(s - mn);
    l = l * esc + pp;
    o0 = o0 * esc + pp * bflo(vu);
    o1 = o1 * esc + pp * bfhi(vu);
    m = mn;
  }
  int h = t >> 3;                  // head this lane's dims belong to
  if (j == 0) { sm[w][h] = m; sl[w][h] = l; }
  so[w][2 * t] = o0;
  so[w][2 * t + 1] = o1;
  __syncthreads();
  if (tid < 128) {
    int d = tid, hh = d >> 4;
    float M = fmaxf(fmaxf(sm[0][hh], sm[1][hh]), fmaxf(sm[2][hh], sm[3][hh]));
    float of = 0.f, L = 0.f;
    #pragma unroll
    for (int ww = 0; ww < 4; ++ww) {
      float e = expf(sm[ww][hh] - M);
      of += so[ww][d] * e;
      L += sl[ww][hh] * e;
    }
    ol[d] = of / L;
  }
  __syncthreads();
  {
    int d = tid & 127, part = tid >> 7;
    float acc = 0.f;
    for (int c = part * 64; c < part * 64 + 64; ++c)
      acc += ol[c] * Wo[c * 128 + d];
    red[part][d] = acc;
    __syncthreads();
    if (part == 0) x[(size_t)n * 128 + d] += red[0][d] + red[1][d];
  }
}

// ---------------------------------------------------------------- FFN
__global__ __launch_bounds__(128) void k_ffn(
    float* __restrict__ x, const float* __restrict__ g, const float* __restrict__ b,
    const float* __restrict__ W1, const float* __restrict__ b1,
    const float* __restrict__ W2, const float* __restrict__ b2) {
  int n = blockIdx.x, d = threadIdx.x;
  __shared__ float red[4];
  __shared__ float h2[128];
  __shared__ float t[512];
  float v = x[(size_t)n * 128 + d];
  float m, r;
  block_meanvar_128(v, m, r, red, d);
  h2[d] = (v - m) * r * g[d] + b[d];
  __syncthreads();
  #pragma unroll
  for (int rr = 0; rr < 4; ++rr) {
    int jj = d + 128 * rr;
    float acc = b1[jj];
    for (int c = 0; c < 128; ++c) acc += h2[c] * W1[c * 512 + jj];
    float inner = 0.7978845608028654f * (acc + 0.044715f * acc * acc * acc);
    t[jj] = 0.5f * acc * (1.0f + tanhf(inner));
  }
  __syncthreads();
  float acc = b2[d];
  for (int jj = 0; jj < 512; ++jj) acc += t[jj] * W2[jj * 128 + d];
  x[(size_t)n * 128 + d] = v + acc;
}

// ---------------------------------------------------------------- final logits
__global__ __launch_bounds__(256) void k_logits(
    const float* __restrict__ x, const float* __restrict__ qpos,
    const int* __restrict__ lss, const int* __restrict__ bids,
    const float* __restrict__ fm, float* __restrict__ out) {
  int n = blockIdx.x, t = threadIdx.x;
  __shared__ float xs[128];
  if (t < 128) xs[t] = x[(size_t)n * 128 + t];
  __syncthreads();
  int wave = t >> 6, lane = t & 63;
  int Hl = lss[0], Wl = lss[1];
  float p0 = qpos[n * 2], p1 = qpos[n * 2 + 1];
  int ci = (int)floorf(p0), cj = (int)floorf(p1);
  size_t bb = (size_t)bids[n] * 256;
  for (int p = wave; p < 49; p += 4) {
    int gi = ci + p / 7 - 3, gj = cj + p % 7 - 3;
    bool v = (gi >= 0) & (gi < Hl) & (gj >= 0) & (gj < Wl);
    int cci = min(max(gi, 0), Hl - 1), ccj = min(max(gj, 0), Wl - 1);
    const float* row = fm + (((bb + cci) * 256 + ccj) * 4 + 0) * 128;
    float s = xs[lane] * row[lane] + xs[lane + 64] * row[lane + 64];
    #pragma unroll
    for (int o = 32; o; o >>= 1) s += __shfl_xor(s, o);
    if (lane == 0) out[(size_t)n * 49 + p] = v ? s : 0.0f;
  }
}

// ---------------------------------------------------------------- launch
extern "C" void kernel_launch(void* const* d_in, const int* in_sizes, int n_in,
                              void* d_out, int out_size, void* d_ws, size_t ws_size,
                              hipStream_t stream) {
  const float* queries = (const float*)d_in[0];
  const int*   offs    = (const int*)d_in[1];
  const float* qpos    = (const float*)d_in[2];
  const float* fm      = (const float*)d_in[3];
  const int*   lss     = (const int*)d_in[4];
  const float* Wq   = (const float*)d_in[5];
  const float* Wk   = (const float*)d_in[6];
  const float* Wv   = (const float*)d_in[7];
  const float* Wo   = (const float*)d_in[8];
  const float* ln1g = (const float*)d_in[9];
  const float* ln1b = (const float*)d_in[10];
  const float* ln2g = (const float*)d_in[11];
  const float* ln2b = (const float*)d_in[12];
  const float* W1   = (const float*)d_in[13];
  const float* b1   = (const float*)d_in[14];
  const float* W2   = (const float*)d_in[15];
  const float* b2   = (const float*)d_in[16];
  const int N = in_sizes[0] / 128;
  const int n_off = in_sizes[1];
  const int NROWS = N * KTOT;

  char* p = (char*)d_ws;
  size_t off = 0;
  auto carve = [&](size_t bytes) {
    void* r = p + off;
    off = (off + bytes + 255) & ~(size_t)255;
    return r;
  };
  float* x    = (float*)carve((size_t)N * 128 * 4);
  float* h    = (float*)carve((size_t)N * 128 * 4);
  float* qb   = (float*)carve((size_t)N * 128 * 4);
  float* qcs  = (float*)carve((size_t)N * 16 * 4);
  int*   bids = (int*)carve((size_t)N * 4);
  unsigned char* valid = (unsigned char*)carve((size_t)N * KTOT);
  float* kcs  = (float*)carve((size_t)N * KTOT * 16 * 4);
  __hip_bfloat16* feats = (__hip_bfloat16*)carve((size_t)NROWS * 128 * 2);
  __hip_bfloat16* kbuf  = (__hip_bfloat16*)carve((size_t)NROWS * 128 * 2);
  __hip_bfloat16* vbuf  = (__hip_bfloat16*)carve((size_t)NROWS * 128 * 2);
  (void)n_in; (void)out_size; (void)ws_size;

  k_prep<<<dim3(N), dim3(128), 0, stream>>>(queries, qpos, offs, n_off, x, qcs, bids);
  k_gather<<<dim3(N), dim3(256), 0, stream>>>(fm, qpos, lss, bids, feats, kcs, valid);
  for (int li = 0; li < 2; ++li) {
    k_ln<<<dim3(N), dim3(128), 0, stream>>>(x, ln1g + li * 128, ln1b + li * 128, h);
    k_qproj<<<dim3(N), dim3(128), 0, stream>>>(h, Wq + (size_t)li * 128 * 128, qcs, qb);
    k_kvproj<<<dim3(384, 2), dim3(256), 0, stream>>>(
        feats, Wk + (size_t)li * 128 * 128, Wv + (size_t)li * 128 * 128,
        kbuf, vbuf, NROWS);
    k_attn2<<<dim3(N), dim3(256), 0, stream>>>(qb, kbuf, vbuf, kcs, valid,
                                               Wo + (size_t)li * 128 * 128, x);
    k_ffn<<<dim3(N), dim3(128), 0, stream>>>(x, ln2g + li * 128, ln2b + li * 128,
                                             W1 + (size_t)li * 128 * 512, b1 + (size_t)li * 512,
                                             W2 + (size_t)li * 512 * 128, b2 + (size_t)li * 128);
  }
  k_logits<<<dim3(N), dim3(256), 0, stream>>>(x, qpos, lss, bids, fm, (float*)d_out);
}